// Round 8
// baseline (4825.073 us; speedup 1.0000x reference)
//
#include <hip/hip_runtime.h>
#include <hip/hip_fp16.h>

#define NB 256
#define NT 512

// ---------------- workspace layout (bytes) ----------------
// 0        barrier region (4096, memset 0): tree barriers only
// 4096     hTenc u64[2][2][2048] 65536 -- tagged enc h (tag<<32|f32) [buf][chain][unit]
// 69632    hTdec u64[2][2][1024] 32768 -- tagged dec h [buf][dir][unit]
// 102400   common f32[512]      2048
// 104448   bsum  f32[2][4096]  32768
// 137216   d1    f32[2][4096]  32768
// 169984   embf  f32[256][1024] 1048576
// 1218560  P     f32[2][8192][256] 16777216
// 17995776 Wcomb fp16[2][4096][1024] 16777216
// 34772992 WhhE  fp16[8192][2048] 33554432
// total fast: 68327424
//
// R7 post-mortem: flag+data split assumed cross-address store ordering
// (flag visible only after data) -- NOT guaranteed for relaxed agent-scope
// stores across XCDs; occasional stale h reads gave absmax 4.3e-2. R8:
// back to self-validating tagged u64 (R6, HW-proven) but polled PER VALUE
// sequentially per thread (stragglers only re-read), keeping R7's dir-split
// chains + packed VGPR-resident weights.

struct KArgs {
  const int *x, *Vg, *Jg;
  const float *emb, *embVg, *embJg;
  const float *encWih, *encWhh, *encBih, *encBhh;
  const float *clsW, *clsB, *latfW, *latfB, *latrW, *latrB, *mixW, *mixB;
  const float *recWih[2], *recWhh[2], *recBih[2], *recBhh[2];
  float* out;
  unsigned* barFull;
  unsigned long long *hTenc, *hTdec;
  float *common, *bsum, *d1, *embf, *P;
  unsigned short *Wcomb, *WhhE;
  int fast;
};

__device__ __forceinline__ unsigned packh2(float lo, float hi) {
  __half2 h = __floats2half2_rn(lo, hi);
  return *(unsigned*)&h;
}
__device__ __forceinline__ float2 h2f2(unsigned u) {
  __half2 h = *(__half2*)&u;
  return __half22float2(h);
}
__device__ __forceinline__ unsigned long long packtag(unsigned tag, float f) {
  return ((unsigned long long)tag << 32) | (unsigned long long)__float_as_uint(f);
}
__device__ __forceinline__ float sigm(float x) { return 1.f / (1.f + __expf(-x)); }
__device__ __forceinline__ float tanh_(float x) { return 2.f / (1.f + __expf(-2.f * x)) - 1.f; }
__device__ __forceinline__ float wred(float v) {
#pragma unroll
  for (int off = 32; off; off >>= 1) v += __shfl_xor(v, off, 64);
  return v;
}
// agent-scope (device-coherent) accesses: bypass non-coherent per-XCD L2.
__device__ __forceinline__ void cstoref(float* p, float v) {
  __hip_atomic_store(p, v, __ATOMIC_RELAXED, __HIP_MEMORY_SCOPE_AGENT);
}
__device__ __forceinline__ float cloadf(const float* p) {
  return __hip_atomic_load(p, __ATOMIC_RELAXED, __HIP_MEMORY_SCOPE_AGENT);
}
__device__ __forceinline__ void cstoreu(unsigned* p, unsigned v) {
  __hip_atomic_store(p, v, __ATOMIC_RELAXED, __HIP_MEMORY_SCOPE_AGENT);
}
__device__ __forceinline__ unsigned long long cload64(const unsigned long long* p) {
  return __hip_atomic_load(p, __ATOMIC_RELAXED, __HIP_MEMORY_SCOPE_AGENT);
}
__device__ __forceinline__ void cstore64(unsigned long long* p, unsigned long long v) {
  __hip_atomic_store(p, v, __ATOMIC_RELAXED, __HIP_MEMORY_SCOPE_AGENT);
}
// Poll one tagged value until its tag matches; straggler-only re-reads.
__device__ __forceinline__ float pollv(const unsigned long long* p, unsigned tg,
                                       unsigned long long v) {
  while ((unsigned)(v >> 32) != tg) {
    __builtin_amdgcn_s_sleep(1);
    v = cload64(p);
  }
  return __uint_as_float((unsigned)v);
}

// Tree barrier (4 uses: setup x2, latents x2). 32B-spaced counters at ws+0.
__device__ __forceinline__ void gbar_tree(unsigned* tree, int idx, unsigned e) {
  const int ls = 8;
  __syncthreads();
  if (threadIdx.x == 0) {
    unsigned* leaf = tree + (idx >> 3) * ls;
    unsigned* root = tree + 32 * ls;
    unsigned* flag = root + ls;
    unsigned old = __hip_atomic_fetch_add(leaf, 1u, __ATOMIC_RELAXED, __HIP_MEMORY_SCOPE_AGENT);
    if (old == e * 8u - 1u) {
      unsigned ro = __hip_atomic_fetch_add(root, 1u, __ATOMIC_RELAXED, __HIP_MEMORY_SCOPE_AGENT);
      if (ro == e * 32u - 1u)
        __hip_atomic_store(flag, e, __ATOMIC_RELAXED, __HIP_MEMORY_SCOPE_AGENT);
    }
    while (__hip_atomic_load(flag, __ATOMIC_RELAXED, __HIP_MEMORY_SCOPE_AGENT) < e)
      __builtin_amdgcn_s_sleep(2);
  }
  __syncthreads();
}

__global__ __launch_bounds__(NT, 2) void rnn2_kernel(KArgs a) {
  __shared__ float smem[16384];  // 64 KB, reused per phase
  const int tid = threadIdx.x;
  const int b = blockIdx.x;
  const int wq = __builtin_amdgcn_readfirstlane(tid >> 6);
  const int lane = tid & 63;

  float* out_recf = a.out + 1280;
  float* out_recr = a.out + 1280 + 262144;
  float* out_embf = a.out + 1280 + 2 * 262144;
  float* out_embr = a.out + 1280 + 3 * 262144;

  // ================= phase 0a =================
  for (int i = tid; i < 2048; i += NT) smem[i] = a.emb[i];
  __syncthreads();
  {  // d1[dir][row] = start_vec @ Wih.T + bih + bhh   (dir0: emb[0], dir1: emb[1])
    int wg = b * 8 + wq;
#pragma unroll 1
    for (int rr = 0; rr < 4; rr++) {
      int idx = wg + rr * 2048;
      int dir = idx >> 12;
      int row = idx & 4095;
      const float* Wih = a.recWih[dir];
      const float* sv = &smem[dir * 1024];
      float acc = 0.f;
#pragma unroll
      for (int kc = 0; kc < 4; kc++) {
        int k = kc * 256 + lane * 4;
        float4 wv = *(const float4*)&Wih[row * 1024 + k];
        float4 ev = *(const float4*)&sv[k];
        acc += wv.x * ev.x + wv.y * ev.y + wv.z * ev.z + wv.w * ev.w;
      }
      acc = wred(acc);
      if (lane == 0)
        cstoref(&a.d1[dir * 4096 + row], acc + a.recBih[dir][row] + a.recBhh[dir][row]);
    }
  }
  const int gtid = b * NT + tid;
  const int GSZ = NB * NT;
  for (int i = gtid; i < 256 * 1024; i += GSZ) {
    int t = i >> 10, e = i & 1023;
    float v = a.emb[a.x[t] * 1024 + e];
    cstoref(&a.embf[i], v);
    out_embf[i] = v;
    out_embr[(255 - t) * 1024 + e] = v;
  }
  if (gtid < 1024) {
    int e = gtid;
    out_recf[e] = a.emb[1024 + e];
    out_recf[255 * 1024 + e] = a.emb[e];
    out_recr[e] = a.emb[e];
    out_recr[255 * 1024 + e] = a.emb[1024 + e];
  }
  if (gtid < 4096) cstore64(&a.hTenc[gtid], packtag(0u, 0.f));  // buf0 h(0)=0, tag 0
  if (gtid < 8192) {
    int dir = gtid >> 12, r = gtid & 4095;
    cstoref(&a.bsum[gtid], a.recBih[dir][r] + a.recBhh[dir][r]);
  }
  if (a.fast) {
    unsigned* W32 = (unsigned*)a.WhhE;
    const int N4 = 8192 * 2048 / 4;
    for (int i = gtid; i < N4; i += GSZ) {
      float4 v = *(const float4*)&a.encWhh[(size_t)i * 4];
      cstoreu(&W32[i * 2], packh2(v.x, v.y));
      cstoreu(&W32[i * 2 + 1], packh2(v.z, v.w));
    }
    unsigned* C32 = (unsigned*)a.Wcomb;
    const int M4 = 4096 * 1024 / 4;
    for (int i = gtid; i < 2 * M4; i += GSZ) {
      int dir = (i >= M4) ? 1 : 0;
      int j = i - dir * M4;
      float4 va = *(const float4*)&a.recWih[dir][(size_t)j * 4];
      float4 vb = *(const float4*)&a.recWhh[dir][(size_t)j * 4];
      cstoreu(&C32[(size_t)dir * (M4 * 2) + j * 2], packh2(va.x + vb.x, va.y + vb.y));
      cstoreu(&C32[(size_t)dir * (M4 * 2) + j * 2 + 1], packh2(va.z + vb.z, va.w + vb.w));
    }
  }
  gbar_tree(a.barFull, b, 1u);

  // ================= phase 0b: P GEMM =================
  {
    const int tdb = b & 7;
    const int rb = (b >> 3) * 256;
    const int td = tdb * 64 + lane;
    const int dirc = td >> 8;
    const int tcol = td & 255;
    float acc[2][16];
#pragma unroll
    for (int p = 0; p < 2; p++)
#pragma unroll
      for (int r = 0; r < 16; r++) acc[p][r] = 0.f;
    const int s_td = tid >> 3;
    const int s_j = tid & 7;
    int std_ = tdb * 64 + s_td;
    int st = std_ & 255;
    const float* s_esrc = &a.embf[((std_ >> 8) ? (255 - st) : st) * 1024];
#pragma unroll 1
    for (int kc = 0; kc < 4; kc++) {
      __syncthreads();
#pragma unroll
      for (int m = 0; m < 8; m++) {
        int kk = s_j * 32 + m * 4;
        float4 v = *(const float4*)&s_esrc[kc * 256 + kk];
        smem[(kk + 0) * 64 + s_td] = v.x;
        smem[(kk + 1) * 64 + s_td] = v.y;
        smem[(kk + 2) * 64 + s_td] = v.z;
        smem[(kk + 3) * 64 + s_td] = v.w;
      }
      __syncthreads();
#pragma unroll
      for (int p = 0; p < 2; p++) {
        int row0 = rb + wq * 32 + p * 16;
#pragma unroll 1
        for (int k4 = 0; k4 < 64; k4++) {
          float e0 = smem[(k4 * 4 + 0) * 64 + lane];
          float e1 = smem[(k4 * 4 + 1) * 64 + lane];
          float e2 = smem[(k4 * 4 + 2) * 64 + lane];
          float e3 = smem[(k4 * 4 + 3) * 64 + lane];
#pragma unroll
          for (int r = 0; r < 16; r++) {
            const float* wp = &a.encWih[(size_t)(row0 + r) * 1024 + kc * 256 + k4 * 4];
            float w0 = wp[0], w1 = wp[1], w2 = wp[2], w3 = wp[3];
            acc[p][r] = fmaf(e0, w0, fmaf(e1, w1, fmaf(e2, w2, fmaf(e3, w3, acc[p][r]))));
          }
        }
      }
    }
#pragma unroll
    for (int p = 0; p < 2; p++)
#pragma unroll
      for (int r = 0; r < 16; r++) {
        int row = rb + wq * 32 + p * 16 + r;
        float bias = a.encBih[row] + a.encBhh[row];
        cstoref(&a.P[(size_t)(dirc * 8192 + row) * 256 + tcol], acc[p][r] + bias);
      }
  }
  gbar_tree(a.barFull, b, 2u);

  // ===== encoder: 256 steps, dir-split chains, tagged per-value exchange ==
  {
    const int c = b >> 7;       // chain (0=fwd, 1=rev)
    const int w = (b & 127) * 8 + wq;  // wave in chain -> units 2w, 2w+1
    const int u0 = 2 * w;
    unsigned wregp[128];  // packed fp16 Whh: [2 units][4 gates][8 chunks][2 u32]
    if (a.fast) {
      const unsigned long long* W64 = (const unsigned long long*)a.WhhE;
#pragma unroll
      for (int uu = 0; uu < 2; uu++)
#pragma unroll
        for (int g = 0; g < 4; g++)
#pragma unroll
          for (int c8 = 0; c8 < 8; c8++) {
            unsigned long long wv =
                cload64(&W64[(size_t)(g * 2048 + u0 + uu) * 512 + c8 * 64 + lane]);
            wregp[((uu * 4 + g) * 8 + c8) * 2] = (unsigned)wv;
            wregp[((uu * 4 + g) * 8 + c8) * 2 + 1] = (unsigned)(wv >> 32);
          }
    }
    float cc0 = 0.f, cc1 = 0.f;
#pragma unroll 1
    for (int t = 0; t < 256; t++) {
      float pv[2][4];  // issue early; latency hides behind poll
#pragma unroll
      for (int uu = 0; uu < 2; uu++)
#pragma unroll
        for (int g = 0; g < 4; g++)
          pv[uu][g] = cloadf(&a.P[(size_t)(c * 8192 + g * 2048 + u0 + uu) * 256 + t]);
      {  // tagged data: 2048 values (my chain), 4 per thread, per-value poll
        const unsigned long long* src = a.hTenc + (t & 1) * 4096 + c * 2048;
        const unsigned tg = (unsigned)t;
        unsigned long long v0 = cload64(&src[tid]);
        unsigned long long v1 = cload64(&src[tid + 512]);
        unsigned long long v2 = cload64(&src[tid + 1024]);
        unsigned long long v3 = cload64(&src[tid + 1536]);
        smem[tid] = pollv(&src[tid], tg, v0);
        smem[tid + 512] = pollv(&src[tid + 512], tg, v1);
        smem[tid + 1024] = pollv(&src[tid + 1024], tg, v2);
        smem[tid + 1536] = pollv(&src[tid + 1536], tg, v3);
      }
      __syncthreads();  // smem ready for compute
      float acc[2][4] = {{0, 0, 0, 0}, {0, 0, 0, 0}};
      if (a.fast) {
#pragma unroll
        for (int c8 = 0; c8 < 8; c8++) {
          float4 hv = *(const float4*)&smem[c8 * 256 + lane * 4];
#pragma unroll
          for (int uu = 0; uu < 2; uu++)
#pragma unroll
            for (int g = 0; g < 4; g++) {
              const int ix = ((uu * 4 + g) * 8 + c8) * 2;
              float2 w01 = h2f2(wregp[ix]);
              float2 w23 = h2f2(wregp[ix + 1]);
              acc[uu][g] = fmaf(w01.x, hv.x, fmaf(w01.y, hv.y,
                           fmaf(w23.x, hv.z, fmaf(w23.y, hv.w, acc[uu][g]))));
            }
        }
      } else {
#pragma unroll 1
        for (int c8 = 0; c8 < 8; c8++) {
          float4 hv = *(const float4*)&smem[c8 * 256 + lane * 4];
#pragma unroll
          for (int uu = 0; uu < 2; uu++)
#pragma unroll
            for (int g = 0; g < 4; g++) {
              float4 wv = *(const float4*)
                  &a.encWhh[(size_t)(g * 2048 + u0 + uu) * 2048 + c8 * 256 + lane * 4];
              acc[uu][g] += wv.x * hv.x + wv.y * hv.y + wv.z * hv.z + wv.w * hv.w;
            }
        }
      }
#pragma unroll
      for (int uu = 0; uu < 2; uu++)
#pragma unroll
        for (int g = 0; g < 4; g++) acc[uu][g] = wred(acc[uu][g]);
      float gi = acc[0][0] + pv[0][0], gf = acc[0][1] + pv[0][1];
      float gg = acc[0][2] + pv[0][2], go = acc[0][3] + pv[0][3];
      cc0 = sigm(gf) * cc0 + sigm(gi) * tanh_(gg);
      float h0v = sigm(go) * tanh_(cc0);
      gi = acc[1][0] + pv[1][0]; gf = acc[1][1] + pv[1][1];
      gg = acc[1][2] + pv[1][2]; go = acc[1][3] + pv[1][3];
      cc1 = sigm(gf) * cc1 + sigm(gi) * tanh_(gg);
      float h1v = sigm(go) * tanh_(cc1);
      if (lane == 0) {  // self-validating tagged stores; no ordering assumed
        unsigned long long* dst = a.hTenc + ((t + 1) & 1) * 4096 + c * 2048;
        cstore64(&dst[u0], packtag((unsigned)(t + 1), h0v));
        cstore64(&dst[u0 + 1], packtag((unsigned)(t + 1), h1v));
      }
      __syncthreads();  // protect smem before next iteration's staging
    }
  }

  // ================= latents (tag-256 poll, then tree-barriers) ==========
  if (b <= 192) {
    {  // stage final h (buf0, tag 256): fwd -> smem[0..2047], rev -> [2048..]
      const unsigned long long* src = a.hTenc;  // buf0
      unsigned long long v[8];
#pragma unroll
      for (int q = 0; q < 8; q++) v[q] = cload64(&src[tid + q * 512]);
#pragma unroll
      for (int q = 0; q < 8; q++)
        smem[tid + q * 512] = pollv(&src[tid + q * 512], 256u, v[q]);
    }
    __syncthreads();
    int wg = b * 8 + wq;
    if (wg < 512) {  // common row
      int r = wg;
      float acc = 0.f;
#pragma unroll 1
      for (int kc = 0; kc < 16; kc++) {
        int k = kc * 256 + lane * 4;
        float4 wv = *(const float4*)&a.clsW[(size_t)r * 4096 + k];
        float4 hv = *(const float4*)&smem[k];
        acc += wv.x * hv.x + wv.y * hv.y + wv.z * hv.z + wv.w * hv.w;
      }
      acc = wred(acc);
      if (lane == 0) cstoref(&a.common[r], tanh_(acc + a.clsB[r]));
    } else if (wg < 1024) {  // lat_f
      int r = wg - 512;
      float acc = 0.f;
#pragma unroll 1
      for (int kc = 0; kc < 8; kc++) {
        int k = kc * 256 + lane * 4;
        float4 wv = *(const float4*)&a.latfW[(size_t)r * 2048 + k];
        float4 hv = *(const float4*)&smem[k];
        acc += wv.x * hv.x + wv.y * hv.y + wv.z * hv.z + wv.w * hv.w;
      }
      acc = wred(acc);
      if (lane == 0) {
        float v = acc + a.latfB[r];
        cstore64(&a.hTdec[64 + r], packtag(0u, v));
        a.out[64 + r] = v;
      }
    } else if (wg < 1536) {  // lat_r
      int r = wg - 1024;
      float acc = 0.f;
#pragma unroll 1
      for (int kc = 0; kc < 8; kc++) {
        int k = kc * 256 + lane * 4;
        float4 wv = *(const float4*)&a.latrW[(size_t)r * 2048 + k];
        float4 hv = *(const float4*)&smem[2048 + k];
        acc += wv.x * hv.x + wv.y * hv.y + wv.z * hv.z + wv.w * hv.w;
      }
      acc = wred(acc);
      if (lane == 0) {
        float v = acc + a.latrB[r];
        cstore64(&a.hTdec[1024 + 64 + r], packtag(0u, v));
        a.out[640 + 64 + r] = v;
      }
    } else if (wg == 1536) {  // vg
      float v = a.embVg[a.Vg[0] * 64 + lane];
      cstore64(&a.hTdec[lane], packtag(0u, v));
      cstore64(&a.hTdec[1024 + lane], packtag(0u, v));
      a.out[lane] = v;
      a.out[640 + lane] = v;
    } else if (wg == 1537) {  // jg
      float v = a.embJg[a.Jg[0] * 64 + lane];
      cstore64(&a.hTdec[576 + lane], packtag(0u, v));
      cstore64(&a.hTdec[1024 + 576 + lane], packtag(0u, v));
      a.out[576 + lane] = v;
      a.out[640 + 576 + lane] = v;
    }
  }
  gbar_tree(a.barFull, b, 3u);  // common + lat + vg/jg complete, grid-wide
  if (b < 48) {  // mix rows 0..383
    int wg = b * 8 + wq;
    smem[tid] = cloadf(&a.common[tid]);
    __syncthreads();
    float acc = 0.f;
#pragma unroll
    for (int kc = 0; kc < 2; kc++) {
      int k = kc * 256 + lane * 4;
      float4 wv = *(const float4*)&a.mixW[(size_t)wg * 512 + k];
      float4 hv = *(const float4*)&smem[k];
      acc += wv.x * hv.x + wv.y * hv.y + wv.z * hv.z + wv.w * hv.w;
    }
    acc = wred(acc);
    if (lane == 0) {
      float v = acc + a.mixB[wg];
      cstore64(&a.hTdec[640 + wg], packtag(0u, v));
      cstore64(&a.hTdec[1024 + 640 + wg], packtag(0u, v));
    }
  }
  gbar_tree(a.barFull, b, 4u);  // full h0 (tag 0) in hTdec buf0, grid-wide

  // ===== decoders: 254 steps, dir-split, tagged per-value exchange ========
  {
    const int dir = b >> 7;
    const int u = (b & 127) * 8 + wq;  // unit 0..1023 in my dir
    float* outrec = dir ? out_recr : out_recf;
    float bs[4];
#pragma unroll
    for (int g = 0; g < 4; g++) bs[g] = cloadf(&a.bsum[dir * 4096 + g * 1024 + u]);
    unsigned wdp[32];  // packed fp16 Wcomb: [4 gates][4 chunks][2 u32]
    if (a.fast) {
      const unsigned long long* C64 = (const unsigned long long*)a.Wcomb;
      const size_t dbase = (size_t)dir * (4096 * 1024 / 4);
#pragma unroll
      for (int g = 0; g < 4; g++)
#pragma unroll
        for (int c4 = 0; c4 < 4; c4++) {
          unsigned long long wv =
              cload64(&C64[dbase + (size_t)(g * 1024 + u) * 256 + c4 * 64 + lane]);
          wdp[(g * 4 + c4) * 2] = (unsigned)wv;
          wdp[(g * 4 + c4) * 2 + 1] = (unsigned)(wv >> 32);
        }
    }
    float c = 0.f;
#pragma unroll 1
    for (int s = 1; s <= 254; s++) {
      {  // tagged data: 1024 values, 2 per thread, per-value poll
        const unsigned long long* src = a.hTdec + ((s - 1) & 1) * 2048 + dir * 1024;
        const unsigned tg = (unsigned)(s - 1);
        unsigned long long v0 = cload64(&src[tid]);
        unsigned long long v1 = cload64(&src[tid + 512]);
        smem[tid] = pollv(&src[tid], tg, v0);
        smem[tid + 512] = pollv(&src[tid + 512], tg, v1);
      }
      __syncthreads();
      float acc[4] = {0, 0, 0, 0};
      if (s == 1) {  // g = d1 + h0 @ Whh.T  (f32 weights, one step)
        const float* Whh = a.recWhh[dir];
#pragma unroll 1
        for (int kc = 0; kc < 4; kc++) {
          int k = kc * 256 + lane * 4;
          float4 hv = *(const float4*)&smem[k];
#pragma unroll
          for (int g = 0; g < 4; g++) {
            float4 wv = *(const float4*)&Whh[(size_t)(g * 1024 + u) * 1024 + k];
            acc[g] += wv.x * hv.x + wv.y * hv.y + wv.z * hv.z + wv.w * hv.w;
          }
        }
      } else if (a.fast) {
#pragma unroll
        for (int c4 = 0; c4 < 4; c4++) {
          float4 hv = *(const float4*)&smem[c4 * 256 + lane * 4];
#pragma unroll
          for (int g = 0; g < 4; g++) {
            const int ix = (g * 4 + c4) * 2;
            float2 w01 = h2f2(wdp[ix]);
            float2 w23 = h2f2(wdp[ix + 1]);
            acc[g] = fmaf(w01.x, hv.x, fmaf(w01.y, hv.y,
                     fmaf(w23.x, hv.z, fmaf(w23.y, hv.w, acc[g]))));
          }
        }
      } else {
        const float* Wi = a.recWih[dir];
        const float* Wh = a.recWhh[dir];
#pragma unroll 1
        for (int kc = 0; kc < 4; kc++) {
          int k = kc * 256 + lane * 4;
          float4 hv = *(const float4*)&smem[k];
#pragma unroll
          for (int g = 0; g < 4; g++) {
            size_t ro = (size_t)(g * 1024 + u) * 1024 + k;
            float4 va = *(const float4*)&Wi[ro];
            float4 vb = *(const float4*)&Wh[ro];
            acc[g] += (va.x + vb.x) * hv.x + (va.y + vb.y) * hv.y +
                      (va.z + vb.z) * hv.z + (va.w + vb.w) * hv.w;
          }
        }
      }
#pragma unroll
      for (int g = 0; g < 4; g++) acc[g] = wred(acc[g]);
      float gi, gf, gg, go;
      if (s == 1) {
        gi = acc[0] + cloadf(&a.d1[dir * 4096 + u]);
        gf = acc[1] + cloadf(&a.d1[dir * 4096 + 1024 + u]);
        gg = acc[2] + cloadf(&a.d1[dir * 4096 + 2048 + u]);
        go = acc[3] + cloadf(&a.d1[dir * 4096 + 3072 + u]);
        c = smem[u];  // c0 = h0
      } else {
        gi = acc[0] + bs[0]; gf = acc[1] + bs[1]; gg = acc[2] + bs[2]; go = acc[3] + bs[3];
      }
      c = sigm(gf) * c + sigm(gi) * tanh_(gg);
      float h2 = sigm(go) * tanh_(c);
      if (lane == 0) {
        outrec[(size_t)(255 - s) * 1024 + u] = h2;
        if (s < 254)
          cstore64(&a.hTdec[(s & 1) * 2048 + dir * 1024 + u], packtag((unsigned)s, h2));
      }
      __syncthreads();  // protect smem before next iteration's staging
    }
  }
}

extern "C" void kernel_launch(void* const* d_in, const int* in_sizes, int n_in,
                              void* d_out, int out_size, void* d_ws, size_t ws_size,
                              hipStream_t stream) {
  (void)in_sizes; (void)n_in; (void)out_size;
  KArgs a;
  a.x = (const int*)d_in[0];
  a.Vg = (const int*)d_in[1];
  a.Jg = (const int*)d_in[2];
  a.emb = (const float*)d_in[3];
  a.embVg = (const float*)d_in[4];
  a.embJg = (const float*)d_in[5];
  a.encWih = (const float*)d_in[6];
  a.encWhh = (const float*)d_in[7];
  a.encBih = (const float*)d_in[8];
  a.encBhh = (const float*)d_in[9];
  a.clsW = (const float*)d_in[10];
  a.clsB = (const float*)d_in[11];
  a.latfW = (const float*)d_in[12];
  a.latfB = (const float*)d_in[13];
  a.latrW = (const float*)d_in[14];
  a.latrB = (const float*)d_in[15];
  a.mixW = (const float*)d_in[16];
  a.mixB = (const float*)d_in[17];
  a.recWih[0] = (const float*)d_in[18];
  a.recWhh[0] = (const float*)d_in[19];
  a.recBih[0] = (const float*)d_in[20];
  a.recBhh[0] = (const float*)d_in[21];
  a.recWih[1] = (const float*)d_in[22];
  a.recWhh[1] = (const float*)d_in[23];
  a.recBih[1] = (const float*)d_in[24];
  a.recBhh[1] = (const float*)d_in[25];
  a.out = (float*)d_out;
  char* ws = (char*)d_ws;
  a.barFull = (unsigned*)ws;
  a.hTenc = (unsigned long long*)(ws + 4096);
  a.hTdec = (unsigned long long*)(ws + 69632);
  a.common = (float*)(ws + 102400);
  a.bsum = (float*)(ws + 104448);
  a.d1 = (float*)(ws + 137216);
  a.embf = (float*)(ws + 169984);
  a.P = (float*)(ws + 1218560);
  a.Wcomb = (unsigned short*)(ws + 17995776);
  a.WhhE = (unsigned short*)(ws + 34772992);
  a.fast = (ws_size >= 68327424ULL) ? 1 : 0;
  hipMemsetAsync(ws, 0, 4096, stream);  // zero tree-barrier counters
  hipLaunchKernelGGL(rnn2_kernel, dim3(NB), dim3(NT), 0, stream, a);
}

// Round 9
// 4592.728 us; speedup vs baseline: 1.0506x; 1.0506x over previous
//
#include <hip/hip_runtime.h>
#include <hip/hip_fp16.h>

#define NB 256
#define NT 512

// ---------------- workspace layout (bytes) ----------------
// 0        barrier region (4096, memset 0): tree barriers only
// 4096     hTenc u64[2][2][2048] 65536 -- tagged enc h (tag<<32|f32) [buf][chain][unit]
// 69632    hTdec u64[2][2][1024] 32768 -- tagged dec h [buf][dir][unit]
// 102400   common f32[512]      2048
// 104448   bsum  f32[2][4096]  32768
// 137216   d1    f32[2][4096]  32768
// 169984   embf  f32[256][1024] 1048576
// 1218560  P     f32[2][8192][256] 16777216
// 17995776 Wcomb fp16[2][4096][1024] 16777216
// 34772992 WhhE  fp16[8192][2048] 33554432
// total fast: 68327424
//
// R8 post-mortem: sequential per-value polls serialized 4 poll latencies and
// multiplied poll rounds ~10x (FETCH 326MB->3.1GB, VALU 26->13%). R9: R6-style
// BATCHED polls (all loads in flight, combined tag check, retry together) +
// producers publish one full 128B line per block via LDS gather.

struct KArgs {
  const int *x, *Vg, *Jg;
  const float *emb, *embVg, *embJg;
  const float *encWih, *encWhh, *encBih, *encBhh;
  const float *clsW, *clsB, *latfW, *latfB, *latrW, *latrB, *mixW, *mixB;
  const float *recWih[2], *recWhh[2], *recBih[2], *recBhh[2];
  float* out;
  unsigned* barFull;
  unsigned long long *hTenc, *hTdec;
  float *common, *bsum, *d1, *embf, *P;
  unsigned short *Wcomb, *WhhE;
  int fast;
};

__device__ __forceinline__ unsigned packh2(float lo, float hi) {
  __half2 h = __floats2half2_rn(lo, hi);
  return *(unsigned*)&h;
}
__device__ __forceinline__ float2 h2f2(unsigned u) {
  __half2 h = *(__half2*)&u;
  return __half22float2(h);
}
__device__ __forceinline__ unsigned long long packtag(unsigned tag, float f) {
  return ((unsigned long long)tag << 32) | (unsigned long long)__float_as_uint(f);
}
__device__ __forceinline__ float sigm(float x) { return 1.f / (1.f + __expf(-x)); }
__device__ __forceinline__ float tanh_(float x) { return 2.f / (1.f + __expf(-2.f * x)) - 1.f; }
__device__ __forceinline__ float wred(float v) {
#pragma unroll
  for (int off = 32; off; off >>= 1) v += __shfl_xor(v, off, 64);
  return v;
}
// agent-scope (device-coherent) accesses: bypass non-coherent per-XCD L2.
__device__ __forceinline__ void cstoref(float* p, float v) {
  __hip_atomic_store(p, v, __ATOMIC_RELAXED, __HIP_MEMORY_SCOPE_AGENT);
}
__device__ __forceinline__ float cloadf(const float* p) {
  return __hip_atomic_load(p, __ATOMIC_RELAXED, __HIP_MEMORY_SCOPE_AGENT);
}
__device__ __forceinline__ void cstoreu(unsigned* p, unsigned v) {
  __hip_atomic_store(p, v, __ATOMIC_RELAXED, __HIP_MEMORY_SCOPE_AGENT);
}
__device__ __forceinline__ unsigned long long cload64(const unsigned long long* p) {
  return __hip_atomic_load(p, __ATOMIC_RELAXED, __HIP_MEMORY_SCOPE_AGENT);
}
__device__ __forceinline__ void cstore64(unsigned long long* p, unsigned long long v) {
  __hip_atomic_store(p, v, __ATOMIC_RELAXED, __HIP_MEMORY_SCOPE_AGENT);
}

// Tree barrier (4 uses: setup x2, latents x2). 32B-spaced counters at ws+0.
__device__ __forceinline__ void gbar_tree(unsigned* tree, int idx, unsigned e) {
  const int ls = 8;
  __syncthreads();
  if (threadIdx.x == 0) {
    unsigned* leaf = tree + (idx >> 3) * ls;
    unsigned* root = tree + 32 * ls;
    unsigned* flag = root + ls;
    unsigned old = __hip_atomic_fetch_add(leaf, 1u, __ATOMIC_RELAXED, __HIP_MEMORY_SCOPE_AGENT);
    if (old == e * 8u - 1u) {
      unsigned ro = __hip_atomic_fetch_add(root, 1u, __ATOMIC_RELAXED, __HIP_MEMORY_SCOPE_AGENT);
      if (ro == e * 32u - 1u)
        __hip_atomic_store(flag, e, __ATOMIC_RELAXED, __HIP_MEMORY_SCOPE_AGENT);
    }
    while (__hip_atomic_load(flag, __ATOMIC_RELAXED, __HIP_MEMORY_SCOPE_AGENT) < e)
      __builtin_amdgcn_s_sleep(2);
  }
  __syncthreads();
}

__global__ __launch_bounds__(NT, 2) void rnn2_kernel(KArgs a) {
  __shared__ float smem[16384];  // 64 KB; [4096..4127] = line-gather staging
  const int tid = threadIdx.x;
  const int b = blockIdx.x;
  const int wq = __builtin_amdgcn_readfirstlane(tid >> 6);
  const int lane = tid & 63;
  unsigned long long* stg = (unsigned long long*)&smem[4096];  // 16 u64

  float* out_recf = a.out + 1280;
  float* out_recr = a.out + 1280 + 262144;
  float* out_embf = a.out + 1280 + 2 * 262144;
  float* out_embr = a.out + 1280 + 3 * 262144;

  // ================= phase 0a =================
  for (int i = tid; i < 2048; i += NT) smem[i] = a.emb[i];
  __syncthreads();
  {  // d1[dir][row] = start_vec @ Wih.T + bih + bhh   (dir0: emb[0], dir1: emb[1])
    int wg = b * 8 + wq;
#pragma unroll 1
    for (int rr = 0; rr < 4; rr++) {
      int idx = wg + rr * 2048;
      int dir = idx >> 12;
      int row = idx & 4095;
      const float* Wih = a.recWih[dir];
      const float* sv = &smem[dir * 1024];
      float acc = 0.f;
#pragma unroll
      for (int kc = 0; kc < 4; kc++) {
        int k = kc * 256 + lane * 4;
        float4 wv = *(const float4*)&Wih[row * 1024 + k];
        float4 ev = *(const float4*)&sv[k];
        acc += wv.x * ev.x + wv.y * ev.y + wv.z * ev.z + wv.w * ev.w;
      }
      acc = wred(acc);
      if (lane == 0)
        cstoref(&a.d1[dir * 4096 + row], acc + a.recBih[dir][row] + a.recBhh[dir][row]);
    }
  }
  const int gtid = b * NT + tid;
  const int GSZ = NB * NT;
  for (int i = gtid; i < 256 * 1024; i += GSZ) {
    int t = i >> 10, e = i & 1023;
    float v = a.emb[a.x[t] * 1024 + e];
    cstoref(&a.embf[i], v);
    out_embf[i] = v;
    out_embr[(255 - t) * 1024 + e] = v;
  }
  if (gtid < 1024) {
    int e = gtid;
    out_recf[e] = a.emb[1024 + e];
    out_recf[255 * 1024 + e] = a.emb[e];
    out_recr[e] = a.emb[e];
    out_recr[255 * 1024 + e] = a.emb[1024 + e];
  }
  if (gtid < 4096) cstore64(&a.hTenc[gtid], packtag(0u, 0.f));  // buf0 h(0)=0, tag 0
  if (gtid < 8192) {
    int dir = gtid >> 12, r = gtid & 4095;
    cstoref(&a.bsum[gtid], a.recBih[dir][r] + a.recBhh[dir][r]);
  }
  if (a.fast) {
    unsigned* W32 = (unsigned*)a.WhhE;
    const int N4 = 8192 * 2048 / 4;
    for (int i = gtid; i < N4; i += GSZ) {
      float4 v = *(const float4*)&a.encWhh[(size_t)i * 4];
      cstoreu(&W32[i * 2], packh2(v.x, v.y));
      cstoreu(&W32[i * 2 + 1], packh2(v.z, v.w));
    }
    unsigned* C32 = (unsigned*)a.Wcomb;
    const int M4 = 4096 * 1024 / 4;
    for (int i = gtid; i < 2 * M4; i += GSZ) {
      int dir = (i >= M4) ? 1 : 0;
      int j = i - dir * M4;
      float4 va = *(const float4*)&a.recWih[dir][(size_t)j * 4];
      float4 vb = *(const float4*)&a.recWhh[dir][(size_t)j * 4];
      cstoreu(&C32[(size_t)dir * (M4 * 2) + j * 2], packh2(va.x + vb.x, va.y + vb.y));
      cstoreu(&C32[(size_t)dir * (M4 * 2) + j * 2 + 1], packh2(va.z + vb.z, va.w + vb.w));
    }
  }
  gbar_tree(a.barFull, b, 1u);

  // ================= phase 0b: P GEMM =================
  {
    const int tdb = b & 7;
    const int rb = (b >> 3) * 256;
    const int td = tdb * 64 + lane;
    const int dirc = td >> 8;
    const int tcol = td & 255;
    float acc[2][16];
#pragma unroll
    for (int p = 0; p < 2; p++)
#pragma unroll
      for (int r = 0; r < 16; r++) acc[p][r] = 0.f;
    const int s_td = tid >> 3;
    const int s_j = tid & 7;
    int std_ = tdb * 64 + s_td;
    int st = std_ & 255;
    const float* s_esrc = &a.embf[((std_ >> 8) ? (255 - st) : st) * 1024];
#pragma unroll 1
    for (int kc = 0; kc < 4; kc++) {
      __syncthreads();
#pragma unroll
      for (int m = 0; m < 8; m++) {
        int kk = s_j * 32 + m * 4;
        float4 v = *(const float4*)&s_esrc[kc * 256 + kk];
        smem[(kk + 0) * 64 + s_td] = v.x;
        smem[(kk + 1) * 64 + s_td] = v.y;
        smem[(kk + 2) * 64 + s_td] = v.z;
        smem[(kk + 3) * 64 + s_td] = v.w;
      }
      __syncthreads();
#pragma unroll
      for (int p = 0; p < 2; p++) {
        int row0 = rb + wq * 32 + p * 16;
#pragma unroll 1
        for (int k4 = 0; k4 < 64; k4++) {
          float e0 = smem[(k4 * 4 + 0) * 64 + lane];
          float e1 = smem[(k4 * 4 + 1) * 64 + lane];
          float e2 = smem[(k4 * 4 + 2) * 64 + lane];
          float e3 = smem[(k4 * 4 + 3) * 64 + lane];
#pragma unroll
          for (int r = 0; r < 16; r++) {
            const float* wp = &a.encWih[(size_t)(row0 + r) * 1024 + kc * 256 + k4 * 4];
            float w0 = wp[0], w1 = wp[1], w2 = wp[2], w3 = wp[3];
            acc[p][r] = fmaf(e0, w0, fmaf(e1, w1, fmaf(e2, w2, fmaf(e3, w3, acc[p][r]))));
          }
        }
      }
    }
#pragma unroll
    for (int p = 0; p < 2; p++)
#pragma unroll
      for (int r = 0; r < 16; r++) {
        int row = rb + wq * 32 + p * 16 + r;
        float bias = a.encBih[row] + a.encBhh[row];
        cstoref(&a.P[(size_t)(dirc * 8192 + row) * 256 + tcol], acc[p][r] + bias);
      }
  }
  gbar_tree(a.barFull, b, 2u);

  // ===== encoder: 256 steps, chain-split, tagged batched-poll exchange ====
  {
    const int c = b >> 7;              // chain (0=fwd, 1=rev)
    const int bc = b & 127;            // block within chain
    const int w = bc * 8 + wq;         // wave in chain -> units 2w, 2w+1
    const int u0 = 2 * w;
    unsigned wregp[128];  // packed fp16 Whh: [2 units][4 gates][8 chunks][2 u32]
    if (a.fast) {
      const unsigned long long* W64 = (const unsigned long long*)a.WhhE;
#pragma unroll
      for (int uu = 0; uu < 2; uu++)
#pragma unroll
        for (int g = 0; g < 4; g++)
#pragma unroll
          for (int c8 = 0; c8 < 8; c8++) {
            unsigned long long wv =
                cload64(&W64[(size_t)(g * 2048 + u0 + uu) * 512 + c8 * 64 + lane]);
            wregp[((uu * 4 + g) * 8 + c8) * 2] = (unsigned)wv;
            wregp[((uu * 4 + g) * 8 + c8) * 2 + 1] = (unsigned)(wv >> 32);
          }
    }
    float cc0 = 0.f, cc1 = 0.f;
#pragma unroll 1
    for (int t = 0; t < 256; t++) {
      float pv[2][4];  // issue early; latency hides behind poll
#pragma unroll
      for (int uu = 0; uu < 2; uu++)
#pragma unroll
        for (int g = 0; g < 4; g++)
          pv[uu][g] = cloadf(&a.P[(size_t)(c * 8192 + g * 2048 + u0 + uu) * 256 + t]);
      {  // batched poll: 4 values/thread in flight, combined tag check
        const unsigned long long* src = a.hTenc + (t & 1) * 4096 + c * 2048;
        const unsigned tg = (unsigned)t;
        unsigned long long v0, v1, v2, v3;
        for (;;) {
          v0 = cload64(&src[tid]);
          v1 = cload64(&src[tid + 512]);
          v2 = cload64(&src[tid + 1024]);
          v3 = cload64(&src[tid + 1536]);
          unsigned bad = (((unsigned)(v0 >> 32)) ^ tg) | (((unsigned)(v1 >> 32)) ^ tg) |
                         (((unsigned)(v2 >> 32)) ^ tg) | (((unsigned)(v3 >> 32)) ^ tg);
          if (!bad) break;
          __builtin_amdgcn_s_sleep(1);
        }
        smem[tid] = __uint_as_float((unsigned)v0);
        smem[tid + 512] = __uint_as_float((unsigned)v1);
        smem[tid + 1024] = __uint_as_float((unsigned)v2);
        smem[tid + 1536] = __uint_as_float((unsigned)v3);
      }
      __syncthreads();  // (A) smem ready for compute
      float acc[2][4] = {{0, 0, 0, 0}, {0, 0, 0, 0}};
      if (a.fast) {
#pragma unroll
        for (int c8 = 0; c8 < 8; c8++) {
          float4 hv = *(const float4*)&smem[c8 * 256 + lane * 4];
#pragma unroll
          for (int uu = 0; uu < 2; uu++)
#pragma unroll
            for (int g = 0; g < 4; g++) {
              const int ix = ((uu * 4 + g) * 8 + c8) * 2;
              float2 w01 = h2f2(wregp[ix]);
              float2 w23 = h2f2(wregp[ix + 1]);
              acc[uu][g] = fmaf(w01.x, hv.x, fmaf(w01.y, hv.y,
                           fmaf(w23.x, hv.z, fmaf(w23.y, hv.w, acc[uu][g]))));
            }
        }
      } else {
#pragma unroll 1
        for (int c8 = 0; c8 < 8; c8++) {
          float4 hv = *(const float4*)&smem[c8 * 256 + lane * 4];
#pragma unroll
          for (int uu = 0; uu < 2; uu++)
#pragma unroll
            for (int g = 0; g < 4; g++) {
              float4 wv = *(const float4*)
                  &a.encWhh[(size_t)(g * 2048 + u0 + uu) * 2048 + c8 * 256 + lane * 4];
              acc[uu][g] += wv.x * hv.x + wv.y * hv.y + wv.z * hv.z + wv.w * hv.w;
            }
        }
      }
#pragma unroll
      for (int uu = 0; uu < 2; uu++)
#pragma unroll
        for (int g = 0; g < 4; g++) acc[uu][g] = wred(acc[uu][g]);
      float gi = acc[0][0] + pv[0][0], gf = acc[0][1] + pv[0][1];
      float gg = acc[0][2] + pv[0][2], go = acc[0][3] + pv[0][3];
      cc0 = sigm(gf) * cc0 + sigm(gi) * tanh_(gg);
      float h0v = sigm(go) * tanh_(cc0);
      gi = acc[1][0] + pv[1][0]; gf = acc[1][1] + pv[1][1];
      gg = acc[1][2] + pv[1][2]; go = acc[1][3] + pv[1][3];
      cc1 = sigm(gf) * cc1 + sigm(gi) * tanh_(cc1 * 0.f + gg);
      float h1v = sigm(go) * tanh_(cc1);
      // gather block's 16 tagged values in LDS, publish as one 128-B line
      if (lane == 0) {
        stg[wq * 2] = packtag((unsigned)(t + 1), h0v);
        stg[wq * 2 + 1] = packtag((unsigned)(t + 1), h1v);
      }
      __syncthreads();  // (B) stage complete; also protects smem for next poll
      if (tid < 16) {
        unsigned long long* dst = a.hTenc + ((t + 1) & 1) * 4096 + c * 2048;
        cstore64(&dst[bc * 16 + tid], stg[tid]);
      }
    }
  }

  // ================= latents (tag-256 batched poll, then tree-barriers) ===
  if (b <= 192) {
    {  // stage final h (buf0, tag 256): fwd -> smem[0..2047], rev -> [2048..]
      const unsigned long long* src = a.hTenc;  // buf0
      unsigned long long v[8];
      for (;;) {
#pragma unroll
        for (int q = 0; q < 8; q++) v[q] = cload64(&src[tid + q * 512]);
        unsigned bad = 0;
#pragma unroll
        for (int q = 0; q < 8; q++) bad |= ((unsigned)(v[q] >> 32)) ^ 256u;
        if (!bad) break;
        __builtin_amdgcn_s_sleep(1);
      }
#pragma unroll
      for (int q = 0; q < 8; q++) smem[tid + q * 512] = __uint_as_float((unsigned)v[q]);
    }
    __syncthreads();
    int wg = b * 8 + wq;
    if (wg < 512) {  // common row
      int r = wg;
      float acc = 0.f;
#pragma unroll 1
      for (int kc = 0; kc < 16; kc++) {
        int k = kc * 256 + lane * 4;
        float4 wv = *(const float4*)&a.clsW[(size_t)r * 4096 + k];
        float4 hv = *(const float4*)&smem[k];
        acc += wv.x * hv.x + wv.y * hv.y + wv.z * hv.z + wv.w * hv.w;
      }
      acc = wred(acc);
      if (lane == 0) cstoref(&a.common[r], tanh_(acc + a.clsB[r]));
    } else if (wg < 1024) {  // lat_f
      int r = wg - 512;
      float acc = 0.f;
#pragma unroll 1
      for (int kc = 0; kc < 8; kc++) {
        int k = kc * 256 + lane * 4;
        float4 wv = *(const float4*)&a.latfW[(size_t)r * 2048 + k];
        float4 hv = *(const float4*)&smem[k];
        acc += wv.x * hv.x + wv.y * hv.y + wv.z * hv.z + wv.w * hv.w;
      }
      acc = wred(acc);
      if (lane == 0) {
        float v = acc + a.latfB[r];
        cstore64(&a.hTdec[64 + r], packtag(0u, v));
        a.out[64 + r] = v;
      }
    } else if (wg < 1536) {  // lat_r
      int r = wg - 1024;
      float acc = 0.f;
#pragma unroll 1
      for (int kc = 0; kc < 8; kc++) {
        int k = kc * 256 + lane * 4;
        float4 wv = *(const float4*)&a.latrW[(size_t)r * 2048 + k];
        float4 hv = *(const float4*)&smem[2048 + k];
        acc += wv.x * hv.x + wv.y * hv.y + wv.z * hv.z + wv.w * hv.w;
      }
      acc = wred(acc);
      if (lane == 0) {
        float v = acc + a.latrB[r];
        cstore64(&a.hTdec[1024 + 64 + r], packtag(0u, v));
        a.out[640 + 64 + r] = v;
      }
    } else if (wg == 1536) {  // vg
      float v = a.embVg[a.Vg[0] * 64 + lane];
      cstore64(&a.hTdec[lane], packtag(0u, v));
      cstore64(&a.hTdec[1024 + lane], packtag(0u, v));
      a.out[lane] = v;
      a.out[640 + lane] = v;
    } else if (wg == 1537) {  // jg
      float v = a.embJg[a.Jg[0] * 64 + lane];
      cstore64(&a.hTdec[576 + lane], packtag(0u, v));
      cstore64(&a.hTdec[1024 + 576 + lane], packtag(0u, v));
      a.out[576 + lane] = v;
      a.out[640 + 576 + lane] = v;
    }
  }
  gbar_tree(a.barFull, b, 3u);  // common + lat + vg/jg complete, grid-wide
  if (b < 48) {  // mix rows 0..383
    int wg = b * 8 + wq;
    smem[tid] = cloadf(&a.common[tid]);
    __syncthreads();
    float acc = 0.f;
#pragma unroll
    for (int kc = 0; kc < 2; kc++) {
      int k = kc * 256 + lane * 4;
      float4 wv = *(const float4*)&a.mixW[(size_t)wg * 512 + k];
      float4 hv = *(const float4*)&smem[k];
      acc += wv.x * hv.x + wv.y * hv.y + wv.z * hv.z + wv.w * hv.w;
    }
    acc = wred(acc);
    if (lane == 0) {
      float v = acc + a.mixB[wg];
      cstore64(&a.hTdec[640 + wg], packtag(0u, v));
      cstore64(&a.hTdec[1024 + 640 + wg], packtag(0u, v));
    }
  }
  gbar_tree(a.barFull, b, 4u);  // full h0 (tag 0) in hTdec buf0, grid-wide

  // ===== decoders: 254 steps, dir-split, tagged batched-poll exchange =====
  {
    const int dir = b >> 7;
    const int bc = b & 127;
    const int u = bc * 8 + wq;  // unit 0..1023 in my dir
    float* outrec = dir ? out_recr : out_recf;
    float bs[4];
#pragma unroll
    for (int g = 0; g < 4; g++) bs[g] = cloadf(&a.bsum[dir * 4096 + g * 1024 + u]);
    unsigned wdp[32];  // packed fp16 Wcomb: [4 gates][4 chunks][2 u32]
    if (a.fast) {
      const unsigned long long* C64 = (const unsigned long long*)a.Wcomb;
      const size_t dbase = (size_t)dir * (4096 * 1024 / 4);
#pragma unroll
      for (int g = 0; g < 4; g++)
#pragma unroll
        for (int c4 = 0; c4 < 4; c4++) {
          unsigned long long wv =
              cload64(&C64[dbase + (size_t)(g * 1024 + u) * 256 + c4 * 64 + lane]);
          wdp[(g * 4 + c4) * 2] = (unsigned)wv;
          wdp[(g * 4 + c4) * 2 + 1] = (unsigned)(wv >> 32);
        }
    }
    float c = 0.f;
#pragma unroll 1
    for (int s = 1; s <= 254; s++) {
      {  // batched poll: 2 values/thread in flight, combined tag check
        const unsigned long long* src = a.hTdec + ((s - 1) & 1) * 2048 + dir * 1024;
        const unsigned tg = (unsigned)(s - 1);
        unsigned long long v0, v1;
        for (;;) {
          v0 = cload64(&src[tid]);
          v1 = cload64(&src[tid + 512]);
          unsigned bad = (((unsigned)(v0 >> 32)) ^ tg) | (((unsigned)(v1 >> 32)) ^ tg);
          if (!bad) break;
          __builtin_amdgcn_s_sleep(1);
        }
        smem[tid] = __uint_as_float((unsigned)v0);
        smem[tid + 512] = __uint_as_float((unsigned)v1);
      }
      __syncthreads();  // (A)
      float acc[4] = {0, 0, 0, 0};
      if (s == 1) {  // g = d1 + h0 @ Whh.T  (f32 weights, one step)
        const float* Whh = a.recWhh[dir];
#pragma unroll 1
        for (int kc = 0; kc < 4; kc++) {
          int k = kc * 256 + lane * 4;
          float4 hv = *(const float4*)&smem[k];
#pragma unroll
          for (int g = 0; g < 4; g++) {
            float4 wv = *(const float4*)&Whh[(size_t)(g * 1024 + u) * 1024 + k];
            acc[g] += wv.x * hv.x + wv.y * hv.y + wv.z * hv.z + wv.w * hv.w;
          }
        }
      } else if (a.fast) {
#pragma unroll
        for (int c4 = 0; c4 < 4; c4++) {
          float4 hv = *(const float4*)&smem[c4 * 256 + lane * 4];
#pragma unroll
          for (int g = 0; g < 4; g++) {
            const int ix = (g * 4 + c4) * 2;
            float2 w01 = h2f2(wdp[ix]);
            float2 w23 = h2f2(wdp[ix + 1]);
            acc[g] = fmaf(w01.x, hv.x, fmaf(w01.y, hv.y,
                     fmaf(w23.x, hv.z, fmaf(w23.y, hv.w, acc[g]))));
          }
        }
      } else {
        const float* Wi = a.recWih[dir];
        const float* Wh = a.recWhh[dir];
#pragma unroll 1
        for (int kc = 0; kc < 4; kc++) {
          int k = kc * 256 + lane * 4;
          float4 hv = *(const float4*)&smem[k];
#pragma unroll
          for (int g = 0; g < 4; g++) {
            size_t ro = (size_t)(g * 1024 + u) * 1024 + k;
            float4 va = *(const float4*)&Wi[ro];
            float4 vb = *(const float4*)&Wh[ro];
            acc[g] += (va.x + vb.x) * hv.x + (va.y + vb.y) * hv.y +
                      (va.z + vb.z) * hv.z + (va.w + vb.w) * hv.w;
          }
        }
      }
#pragma unroll
      for (int g = 0; g < 4; g++) acc[g] = wred(acc[g]);
      float gi, gf, gg, go;
      if (s == 1) {
        gi = acc[0] + cloadf(&a.d1[dir * 4096 + u]);
        gf = acc[1] + cloadf(&a.d1[dir * 4096 + 1024 + u]);
        gg = acc[2] + cloadf(&a.d1[dir * 4096 + 2048 + u]);
        go = acc[3] + cloadf(&a.d1[dir * 4096 + 3072 + u]);
        c = smem[u];  // c0 = h0
      } else {
        gi = acc[0] + bs[0]; gf = acc[1] + bs[1]; gg = acc[2] + bs[2]; go = acc[3] + bs[3];
      }
      c = sigm(gf) * c + sigm(gi) * tanh_(gg);
      float h2 = sigm(go) * tanh_(c);
      if (lane == 0) {
        outrec[(size_t)(255 - s) * 1024 + u] = h2;
        stg[wq] = packtag((unsigned)s, h2);
      }
      __syncthreads();  // (B) stage complete; protects smem for next poll
      if (tid < 8 && s < 254) {
        unsigned long long* dst = a.hTdec + (s & 1) * 2048 + dir * 1024;
        cstore64(&dst[bc * 8 + tid], stg[tid]);
      }
    }
  }
}

extern "C" void kernel_launch(void* const* d_in, const int* in_sizes, int n_in,
                              void* d_out, int out_size, void* d_ws, size_t ws_size,
                              hipStream_t stream) {
  (void)in_sizes; (void)n_in; (void)out_size;
  KArgs a;
  a.x = (const int*)d_in[0];
  a.Vg = (const int*)d_in[1];
  a.Jg = (const int*)d_in[2];
  a.emb = (const float*)d_in[3];
  a.embVg = (const float*)d_in[4];
  a.embJg = (const float*)d_in[5];
  a.encWih = (const float*)d_in[6];
  a.encWhh = (const float*)d_in[7];
  a.encBih = (const float*)d_in[8];
  a.encBhh = (const float*)d_in[9];
  a.clsW = (const float*)d_in[10];
  a.clsB = (const float*)d_in[11];
  a.latfW = (const float*)d_in[12];
  a.latfB = (const float*)d_in[13];
  a.latrW = (const float*)d_in[14];
  a.latrB = (const float*)d_in[15];
  a.mixW = (const float*)d_in[16];
  a.mixB = (const float*)d_in[17];
  a.recWih[0] = (const float*)d_in[18];
  a.recWhh[0] = (const float*)d_in[19];
  a.recBih[0] = (const float*)d_in[20];
  a.recBhh[0] = (const float*)d_in[21];
  a.recWih[1] = (const float*)d_in[22];
  a.recWhh[1] = (const float*)d_in[23];
  a.recBih[1] = (const float*)d_in[24];
  a.recBhh[1] = (const float*)d_in[25];
  a.out = (float*)d_out;
  char* ws = (char*)d_ws;
  a.barFull = (unsigned*)ws;
  a.hTenc = (unsigned long long*)(ws + 4096);
  a.hTdec = (unsigned long long*)(ws + 69632);
  a.common = (float*)(ws + 102400);
  a.bsum = (float*)(ws + 104448);
  a.d1 = (float*)(ws + 137216);
  a.embf = (float*)(ws + 169984);
  a.P = (float*)(ws + 1218560);
  a.Wcomb = (unsigned short*)(ws + 17995776);
  a.WhhE = (unsigned short*)(ws + 34772992);
  a.fast = (ws_size >= 68327424ULL) ? 1 : 0;
  hipMemsetAsync(ws, 0, 4096, stream);  // zero tree-barrier counters
  hipLaunchKernelGGL(rnn2_kernel, dim3(NB), dim3(NT), 0, stream, a);
}